// Round 14
// baseline (519.008 us; speedup 1.0000x reference)
//
#include <hip/hip_runtime.h>
#include <stdint.h>

#define NN 128
#define BB 4096
#define HH 32

typedef float f4 __attribute__((ext_vector_type(4)));

// Pre-pass: bit-pack A transposed. bit d of word (b,node) = (A[b][d][node] != 0).
// d-quartered for occupancy — BB*128 threads (8192 waves = 8/SIMD).
__global__ __launch_bounds__(256) void pack_bits(const float* __restrict__ A,
                                                 ulonglong2* __restrict__ bitsT) {
    const int tid = blockIdx.x * 256 + threadIdx.x;   // BB*128 threads total
    const int b  = tid >> 7;
    const int q  = (tid >> 5) & 3;        // which 32-row d-quarter
    const int ng = (tid & 31) << 2;       // this thread's 4 nodes
    const float* Ab = A + (size_t)b * (NN * NN) + (size_t)(q * 32) * NN + ng;
    unsigned int w[4] = {0u, 0u, 0u, 0u};
#pragma unroll 8
    for (int d = 0; d < 32; ++d) {
        f4 v = __builtin_nontemporal_load((const f4*)(Ab + (size_t)d * NN));
        const unsigned int bit = 1u << d;
        if (v[0] != 0.f) w[0] |= bit;
        if (v[1] != 0.f) w[1] |= bit;
        if (v[2] != 0.f) w[2] |= bit;
        if (v[3] != 0.f) w[3] |= bit;
    }
    unsigned int* o = (unsigned int*)(bitsT + (size_t)b * NN + ng);
#pragma unroll
    for (int i = 0; i < 4; ++i) o[i * 4 + q] = w[i];
}

__device__ __forceinline__ int mbcnt64(unsigned long long m) {
    return __builtin_amdgcn_mbcnt_hi((unsigned int)(m >> 32),
           __builtin_amdgcn_mbcnt_lo((unsigned int)m, 0));
}
__device__ __forceinline__ unsigned long long rfl64(unsigned long long v) {
    unsigned int lo = __builtin_amdgcn_readfirstlane((unsigned int)v);
    unsigned int hi = __builtin_amdgcn_readfirstlane((unsigned int)(v >> 32));
    return ((unsigned long long)hi << 32) | lo;
}

// Per-step pipeline state, double-buffered via the unroll-2 (register renaming).
struct Pipe {
    int node;                       // as SC: node of this step; repurposed at
                                    //   phase 5 to hold node_{T+2}
    int cnt;                        // entry count for this step
    unsigned long long bw0, bw1;    // bit words of this node
    ulonglong2 vb;                  // raw bits prefetch (for the T+2 step)
    float w2v, b1v, xv, b2v, w1xv, wfr;
};

// v15 = r13 with the cnt=0 padding hole closed:
//   r13 FAILED accuracy because top=(cnt+7)&~7 gives top=0 at cnt=0 -> no
//   padding writes, yet chunk 0's FMAs are UNCONDITIONAL -> stale entries
//   (real nonzero values from 2 steps earlier) contaminated the sum on
//   every zero-parent step. Invariant: every executing chunk k needs
//   top >= 8(k+1); chunk 0 always executes -> top >= 8 ALWAYS.
//   Fix: top = cnt>32 ? 48 : max(8, (cnt+7)&~7).
//  (a) FMA quads per 8-entry chunk only when cnt>8k (accumulators defined
//      outside the branches -> definedness-safe).
//  (b) padding trimmed to max(8,(cnt+7)&~7) (48 if cnt>32).
//  (c) prologue zeroes entries 0..47 of both buffers (r12's t=0 crash fix).
#define STEP(T, ECUR, ENXT, SC, SN, BCUR, BNXT)                              \
  {                                                                          \
    const int nodeT = SC.node;                                               \
    const char* WnB = (const char*)(W1 + (size_t)nodeT * ((NN + 1) * HH));   \
    /* 0: W loads for T — entries 0..15 always (early issue slot) */         \
    float wv[16];                                                            \
    _Pragma("unroll")                                                        \
    for (int q = 0; q < 4; ++q) {                                            \
        wv[2*q]   = *(const float*)(WnB + (__float_as_int(ECUR[q][1]) + j4));\
        wv[2*q+1] = *(const float*)(WnB + (__float_as_int(ECUR[q][3]) + j4));\
    }                                                                        \
    /* 0b: entries 16..31 — load if present, else defined zeros */           \
    if (SC_cnt_snap > 16) {                                                  \
        _Pragma("unroll")                                                    \
        for (int q = 4; q < 8; ++q) {                                        \
            wv[2*q]   = *(const float*)(WnB +                                \
                            (__float_as_int(ECUR[q][1]) + j4));              \
            wv[2*q+1] = *(const float*)(WnB +                                \
                            (__float_as_int(ECUR[q][3]) + j4));              \
        }                                                                    \
    } else {                                                                 \
        _Pragma("unroll")                                                    \
        for (int i = 8; i < 16; ++i) wv[i] = 0.f;                            \
    }                                                                        \
    /* 1: apply pending update from T-1 */                                   \
    if ((T) > 0) {                                                           \
        if (dob != pend_node && lane == (pend_node & 63)) {                  \
            if (pend_node < 64) out0 = pend_val; else out1 = pend_val;       \
        }                                                                    \
        if (pend_node < 64) nz0 |= 1ull << pend_node;                        \
        else                nz1 |= 1ull << (pend_node - 64);                 \
    }                                                                        \
    /* 2: masks for T+1 (node_T excluded -> fresh path covers) */            \
    const unsigned long long bw0n = rfl64(SN.vb.x);                          \
    const unsigned long long bw1n = rfl64(SN.vb.y);                          \
    const unsigned long long m0 = nz0 & bw0n;                                \
    const unsigned long long m1 = nz1 & bw1n;                                \
    const int c0n  = __popcll(m0);                                           \
    const int cntn = c0n + __popcll(m1);                                     \
    SN.bw0 = bw0n; SN.bw1 = bw1n; SN.cnt = cntn;                             \
    /* 3: compaction writes for T+1 (deinterleaved by entry parity) */       \
    {                                                                        \
        const int p0 = mbcnt64(m0);                                          \
        if (m0 & lanebit)                                                    \
            entb[BNXT][p0 & 1][p0 >> 1] = make_float2(out0, fidx0);          \
        const int p1 = c0n + mbcnt64(m1);                                    \
        if (m1 & lanebit)                                                    \
            entb[BNXT][p1 & 1][p1 >> 1] = make_float2(out1, fidx1);          \
        const int tpad = (cntn + 7) & ~7;                                    \
        const int top = (cntn > 32) ? 48 : ((tpad < 8) ? 8 : tpad);          \
        const int pp = cntn + lane;                                          \
        if (pp < top)                                                        \
            entb[BNXT][pp & 1][pp >> 1] = make_float2(0.f, __int_as_float(0));\
    }                                                                        \
    /* 4: entry ds_reads for T+1 (same-wave DS in-order, no barrier) */      \
    {                                                                        \
        const f4* eb = (const f4*)&entb[BNXT][half][0];                      \
        _Pragma("unroll")                                                    \
        for (int q = 0; q < 8; ++q) ENXT[q] = eb[q];                         \
    }                                                                        \
    /* 5: prefetch node_{T+2} bits; T+1 epilogue scalars */                  \
    const int node2 = ((T) + 2 < NN)                                         \
        ? __builtin_amdgcn_readfirstlane(ord[(T) + 2]) : 0;                  \
    SC.node = node2;                                                         \
    SC.vb   = bb[node2];                                                     \
    {                                                                        \
        const float* Wn_nxt = W1 + (size_t)SN.node * ((NN + 1) * HH);        \
        SN.w2v  = W2[SN.node * HH + j];                                      \
        SN.b1v  = b1[SN.node * HH + j];                                      \
        SN.xv   = x[b * NN + SN.node];                                       \
        SN.b2v  = b2[SN.node];                                               \
        SN.w1xv = Wn_nxt[NN * HH + j];                                       \
        SN.wfr  = Wn_nxt[(nodeT << 5) + j];                                  \
    }                                                                        \
    /* 6: compute-critical section — per-chunk FMA skip */                   \
    __builtin_amdgcn_s_setprio(1);                                           \
    float a0 = 0.f, a1 = 0.f, a2 = 0.f, a3 = 0.f;                            \
    /* chunk 0: entries 0..7 (always; top>=8 guarantees real-or-zero) */     \
    a0 += ECUR[0][0] * wv[0];  a1 += ECUR[0][2] * wv[1];                     \
    a2 += ECUR[1][0] * wv[2];  a3 += ECUR[1][2] * wv[3];                     \
    if (SC_cnt_snap > 8) {   /* chunk 1: entries 8..15 */                    \
        a0 += ECUR[2][0] * wv[4];  a1 += ECUR[2][2] * wv[5];                 \
        a2 += ECUR[3][0] * wv[6];  a3 += ECUR[3][2] * wv[7];                 \
    }                                                                        \
    if (SC_cnt_snap > 16) {  /* chunk 2: entries 16..23 */                   \
        a0 += ECUR[4][0] * wv[8];  a1 += ECUR[4][2] * wv[9];                 \
        a2 += ECUR[5][0] * wv[10]; a3 += ECUR[5][2] * wv[11];                \
    }                                                                        \
    if (SC_cnt_snap > 24) {  /* chunk 3: entries 24..31 */                   \
        a0 += ECUR[6][0] * wv[12]; a1 += ECUR[6][2] * wv[13];                \
        a2 += ECUR[7][0] * wv[14]; a3 += ECUR[7][2] * wv[15];                \
    }                                                                        \
    /* 6b: entries 32..47 — branch-LOCAL fully-defined arrays */             \
    if (SC_cnt_snap > 32) {                                                  \
        f4 e3[4];                                                            \
        const f4* eb3 = (const f4*)&entb[BCUR][half][16];                    \
        _Pragma("unroll")                                                    \
        for (int q = 0; q < 4; ++q) e3[q] = eb3[q];                          \
        float w3[8];                                                         \
        _Pragma("unroll")                                                    \
        for (int q = 0; q < 4; ++q) {                                        \
            w3[2*q]   = *(const float*)(WnB + (__float_as_int(e3[q][1]) + j4));\
            w3[2*q+1] = *(const float*)(WnB + (__float_as_int(e3[q][3]) + j4));\
        }                                                                    \
        _Pragma("unroll")                                                    \
        for (int q = 0; q < 4; ++q) {                                        \
            a0 += e3[q][0] * w3[2*q];                                        \
            a1 += e3[q][2] * w3[2*q+1];                                      \
        }                                                                    \
        /* 6c: entries 48+ (rare statistical tail; correctness guard) */     \
        if (SC_cnt_snap > 48) {                                              \
            for (int i = 24; 2 * i + half < SC_cnt_snap; ++i) {              \
                float2 e = entb[BCUR][half][i];                              \
                a2 += e.x * *(const float*)(WnB + (__float_as_int(e.y) + j4));\
            }                                                                \
        }                                                                    \
    }                                                                        \
    float acc = (a0 + a1) + (a2 + a3);                                       \
    /* 8 */                                                                  \
    float accT = acc + __shfl_xor(acc, 32);                                  \
    const bool fc = ((T) > 0) && (dob != pend_node) &&                       \
        ((((pend_node < 64) ? (SC.bw0 >> pend_node)                          \
                            : (SC.bw1 >> (pend_node - 64)))) & 1ull);        \
    accT += (fc ? pend_val : 0.f) * SC.wfr;                                  \
    accT += SC.xv * SC.w1xv;                                                 \
    accT += SC.b1v;                                                          \
    const float hv = (accT > 0.f) ? accT : 0.01f * accT;                     \
    float pr = hv * SC.w2v;                                                  \
    pr += __int_as_float(__builtin_amdgcn_update_dpp(                        \
             0, __float_as_int(pr), 0xB1, 0xF, 0xF, true));                  \
    pr += __int_as_float(__builtin_amdgcn_update_dpp(                        \
             0, __float_as_int(pr), 0x4E, 0xF, 0xF, true));                  \
    pr += __int_as_float(__builtin_amdgcn_update_dpp(                        \
             0, __float_as_int(pr), 0x141, 0xF, 0xF, true));                 \
    pr += __int_as_float(__builtin_amdgcn_update_dpp(                        \
             0, __float_as_int(pr), 0x140, 0xF, 0xF, true));                 \
    pr += __shfl_xor(pr, 16);                                                \
    const float outv = pr + SC.b2v;                                          \
    __builtin_amdgcn_s_setprio(0);                                           \
    pend_node = nodeT; pend_val = outv;                                      \
  }

__global__ __launch_bounds__(64, 4) void cond_mlp(
    const float* __restrict__ x, const float* __restrict__ u,
    const float* __restrict__ W1, const float* __restrict__ b1,
    const float* __restrict__ W2, const float* __restrict__ b2,
    const int* __restrict__ order, const int* __restrict__ do_idxs,
    const ulonglong2* __restrict__ bitsT, float* __restrict__ out)
{
    const int b = blockIdx.x;
    const int lane = threadIdx.x;
    const int j = lane & 31;
    const int j4 = j << 2;
    const int half = lane >> 5;

    // [buf][entry parity][entry>>1]; inner row 68*8=544B (16B-aligned)
    __shared__ __align__(16) float2 entb[2][2][68];

    const float ub = u[b];
    const int dob = __builtin_amdgcn_readfirstlane(do_idxs[b]);
    float out0 = (dob == lane) ? ub : 0.f;
    float out1 = (dob == lane + 64) ? ub : 0.f;

    unsigned long long nz0 = (dob >= 0 && dob < 64) ? (1ull << dob) : 0ull;
    unsigned long long nz1 = (dob >= 64) ? (1ull << (dob - 64)) : 0ull;

    const int* ord = order + b * NN;
    const ulonglong2* bb = bitsT + (size_t)b * NN;

    const unsigned long long lanebit = 1ull << lane;
    // W1 row BYTE offsets (d * HH * 4 = d<<7)
    const float fidx0 = __int_as_float(lane << 7);
    const float fidx1 = __int_as_float((lane + 64) << 7);

    // ---- prologue: init entries 0..47 of BOTH buffers to (0, offset 0) ----
    for (int i = lane; i < 96; i += 64) {
        const int buf = i / 48;
        const int e   = i - buf * 48;
        entb[buf][e & 1][e >> 1] = make_float2(0.f, __int_as_float(0));
    }

    // ---- prologue: fill SA (step 0) and SB (step 1 prefetch) ----
    Pipe SA, SB;
    SA.node = __builtin_amdgcn_readfirstlane(ord[0]);
    SB.node = __builtin_amdgcn_readfirstlane(ord[1]);
    SB.vb = bb[SB.node];
    SA.vb = bb[SA.node];   // consumed immediately below for step 0's masks

    SA.bw0 = rfl64(SA.vb.x);
    SA.bw1 = rfl64(SA.vb.y);
    f4 eA[8], eB[8];
    {
        const unsigned long long m0 = nz0 & SA.bw0;
        const unsigned long long m1 = nz1 & SA.bw1;
        const int c0 = __popcll(m0);
        SA.cnt = c0 + __popcll(m1);
        const int p0 = mbcnt64(m0);
        if (m0 & lanebit) entb[0][p0 & 1][p0 >> 1] = make_float2(out0, fidx0);
        const int p1 = c0 + mbcnt64(m1);
        if (m1 & lanebit) entb[0][p1 & 1][p1 >> 1] = make_float2(out1, fidx1);
        // prologue already zeroed everything; no extra padding writes needed
        const f4* eb = (const f4*)&entb[0][half][0];
#pragma unroll
        for (int q = 0; q < 8; ++q) eA[q] = eb[q];
    }
    {
        const float* Wn0 = W1 + (size_t)SA.node * ((NN + 1) * HH);
        SA.w2v  = W2[SA.node * HH + j];
        SA.b1v  = b1[SA.node * HH + j];
        SA.xv   = x[b * NN + SA.node];
        SA.b2v  = b2[SA.node];
        SA.w1xv = Wn0[NN * HH + j];
        SA.wfr  = 0.f;
    }

    int pend_node = 0;
    float pend_val = 0.f;

    // ---- main loop: unroll-2 alternates (eA,SA,buf0) / (eB,SB,buf1) ----
    for (int t = 0; t < NN; t += 2) {
        const int SC_cnt_snap0 = SA.cnt;
        { const int SC_cnt_snap = SC_cnt_snap0;
          STEP(t,     eA, eB, SA, SB, 0, 1) }
        const int SC_cnt_snap1 = SB.cnt;
        { const int SC_cnt_snap = SC_cnt_snap1;
          STEP(t + 1, eB, eA, SB, SA, 1, 0) }
    }

    // apply final pending update (from step NN-1)
    if (dob != pend_node && lane == (pend_node & 63)) {
        if (pend_node < 64) out0 = pend_val; else out1 = pend_val;
    }

    out[b * NN + lane] = out0;
    out[b * NN + 64 + lane] = out1;
}

extern "C" void kernel_launch(void* const* d_in, const int* in_sizes, int n_in,
                              void* d_out, int out_size, void* d_ws, size_t ws_size,
                              hipStream_t stream) {
    const float* x   = (const float*)d_in[0];
    const float* A   = (const float*)d_in[1];
    const float* u   = (const float*)d_in[2];
    const float* W1  = (const float*)d_in[3];
    const float* b1  = (const float*)d_in[4];
    const float* W2  = (const float*)d_in[5];
    const float* b2  = (const float*)d_in[6];
    const int* order = (const int*)d_in[7];
    const int* dox   = (const int*)d_in[8];

    ulonglong2* bitsT = (ulonglong2*)d_ws;  // 4096*128*16 B = 8 MB

    pack_bits<<<(BB * 128) / 256, 256, 0, stream>>>(A, bitsT);
    cond_mlp<<<BB, 64, 0, stream>>>(x, u, W1, b1, W2, b2, order, dox,
                                    bitsT, (float*)d_out);
}

// Round 15
// 508.775 us; speedup vs baseline: 1.0201x; 1.0201x over previous
//
#include <hip/hip_runtime.h>
#include <stdint.h>

#define NN 128
#define BB 4096
#define HH 32

typedef float f4 __attribute__((ext_vector_type(4)));

// Pre-pass: bit-pack A transposed. bit d of word (b,node) = (A[b][d][node] != 0).
// d-quartered for occupancy — BB*128 threads (8192 waves = 8/SIMD).
__global__ __launch_bounds__(256) void pack_bits(const float* __restrict__ A,
                                                 ulonglong2* __restrict__ bitsT) {
    const int tid = blockIdx.x * 256 + threadIdx.x;   // BB*128 threads total
    const int b  = tid >> 7;
    const int q  = (tid >> 5) & 3;        // which 32-row d-quarter
    const int ng = (tid & 31) << 2;       // this thread's 4 nodes
    const float* Ab = A + (size_t)b * (NN * NN) + (size_t)(q * 32) * NN + ng;
    unsigned int w[4] = {0u, 0u, 0u, 0u};
#pragma unroll 8
    for (int d = 0; d < 32; ++d) {
        f4 v = __builtin_nontemporal_load((const f4*)(Ab + (size_t)d * NN));
        const unsigned int bit = 1u << d;
        if (v[0] != 0.f) w[0] |= bit;
        if (v[1] != 0.f) w[1] |= bit;
        if (v[2] != 0.f) w[2] |= bit;
        if (v[3] != 0.f) w[3] |= bit;
    }
    unsigned int* o = (unsigned int*)(bitsT + (size_t)b * NN + ng);
#pragma unroll
    for (int i = 0; i < 4; ++i) o[i * 4 + q] = w[i];
}

__device__ __forceinline__ int mbcnt64(unsigned long long m) {
    return __builtin_amdgcn_mbcnt_hi((unsigned int)(m >> 32),
           __builtin_amdgcn_mbcnt_lo((unsigned int)m, 0));
}
__device__ __forceinline__ unsigned long long rfl64(unsigned long long v) {
    unsigned int lo = __builtin_amdgcn_readfirstlane((unsigned int)v);
    unsigned int hi = __builtin_amdgcn_readfirstlane((unsigned int)(v >> 32));
    return ((unsigned long long)hi << 32) | lo;
}

// Per-step pipeline state, double-buffered via the unroll-2 (register renaming).
struct Pipe {
    int node;                       // as SC: node of this step; repurposed at
                                    //   phase 5 to hold node_{T+2}
    int cnt;                        // entry count for this step
    unsigned long long bw0, bw1;    // bit words of this node
    ulonglong2 vb;                  // raw bits prefetch (for the T+2 step)
    float w2v, b1v, xv, b2v, w1xv, wfr;
};

// FINAL (session best, r11): one-step software pipeline + branch-free static
// 32-entry gather. Verified 174.0us cond_mlp / 514us total / 56 VGPR / no
// spill. Structure:
//   - compaction for T+1 built from state <= T-1 (node_T's contribution is
//     the in-register "fresh term" at T+1 -> cross-step serial chain is one
//     cndmask+FMA, not a full LDS round-trip)
//   - W rows for step T load at step TOP from register-resident byte offsets
//     (ds_read at T-1); entry ds_reads for T+1 issue right after compaction
//     writes (same-wave DS in-order, no barrier, no lgkmcnt drain)
//   - entries 16..31's W loads predicated with FULL else-zero definition
//     (registers, not scratch); FMAs unconditional (zero-weight padding)
//   - DPP xor1/2/4/8 + shfl_xor16 reduction; unroll-2 register renaming
// REFUTED alternatives (kept for the record): per-chunk FMA skip (r12-r14:
// crash/wrong/+4% slower — branches fragment the schedulable block), W-loads
// a full step ahead (r9: spill + zero-slack lgkmcnt), SALU bit-walk gather
// (r3: serial PULL chain on VALU), per-step __syncthreads (r0: vmcnt drain).
#define STEP(T, ECUR, ENXT, SC, SN, BCUR, BNXT)                              \
  {                                                                          \
    const int nodeT = SC.node;                                               \
    const char* WnB = (const char*)(W1 + (size_t)nodeT * ((NN + 1) * HH));   \
    /* 0: W loads for T — entries 0..15 always (early issue slot) */         \
    float wv[16];                                                            \
    _Pragma("unroll")                                                        \
    for (int q = 0; q < 4; ++q) {                                            \
        wv[2*q]   = *(const float*)(WnB + (__float_as_int(ECUR[q][1]) + j4));\
        wv[2*q+1] = *(const float*)(WnB + (__float_as_int(ECUR[q][3]) + j4));\
    }                                                                        \
    /* 0b: entries 16..31 — load if present, else defined zeros */           \
    if (SC_cnt_snap > 16) {                                                  \
        _Pragma("unroll")                                                    \
        for (int q = 4; q < 8; ++q) {                                        \
            wv[2*q]   = *(const float*)(WnB +                                \
                            (__float_as_int(ECUR[q][1]) + j4));              \
            wv[2*q+1] = *(const float*)(WnB +                                \
                            (__float_as_int(ECUR[q][3]) + j4));              \
        }                                                                    \
    } else {                                                                 \
        _Pragma("unroll")                                                    \
        for (int i = 8; i < 16; ++i) wv[i] = 0.f;                            \
    }                                                                        \
    /* 1: apply pending update from T-1 */                                   \
    if ((T) > 0) {                                                           \
        if (dob != pend_node && lane == (pend_node & 63)) {                  \
            if (pend_node < 64) out0 = pend_val; else out1 = pend_val;       \
        }                                                                    \
        if (pend_node < 64) nz0 |= 1ull << pend_node;                        \
        else                nz1 |= 1ull << (pend_node - 64);                 \
    }                                                                        \
    /* 2: masks for T+1 (node_T excluded -> fresh path covers) */            \
    const unsigned long long bw0n = rfl64(SN.vb.x);                          \
    const unsigned long long bw1n = rfl64(SN.vb.y);                          \
    const unsigned long long m0 = nz0 & bw0n;                                \
    const unsigned long long m1 = nz1 & bw1n;                                \
    const int c0n  = __popcll(m0);                                           \
    const int cntn = c0n + __popcll(m1);                                     \
    SN.bw0 = bw0n; SN.bw1 = bw1n; SN.cnt = cntn;                             \
    /* 3: compaction writes for T+1 (deinterleaved by entry parity) */       \
    {                                                                        \
        const int p0 = mbcnt64(m0);                                          \
        if (m0 & lanebit)                                                    \
            entb[BNXT][p0 & 1][p0 >> 1] = make_float2(out0, fidx0);          \
        const int p1 = c0n + mbcnt64(m1);                                    \
        if (m1 & lanebit)                                                    \
            entb[BNXT][p1 & 1][p1 >> 1] = make_float2(out1, fidx1);          \
        const int top = (cntn > 32) ? 48 : 32;                               \
        const int pp = cntn + lane;                                          \
        if (pp < top)                                                        \
            entb[BNXT][pp & 1][pp >> 1] = make_float2(0.f, __int_as_float(0));\
    }                                                                        \
    /* 4: entry ds_reads for T+1 (same-wave DS in-order, no barrier) */      \
    {                                                                        \
        const f4* eb = (const f4*)&entb[BNXT][half][0];                      \
        _Pragma("unroll")                                                    \
        for (int q = 0; q < 8; ++q) ENXT[q] = eb[q];                         \
    }                                                                        \
    /* 5: prefetch node_{T+2} bits; T+1 epilogue scalars */                  \
    const int node2 = ((T) + 2 < NN)                                         \
        ? __builtin_amdgcn_readfirstlane(ord[(T) + 2]) : 0;                  \
    SC.node = node2;                                                         \
    SC.vb   = bb[node2];                                                     \
    {                                                                        \
        const float* Wn_nxt = W1 + (size_t)SN.node * ((NN + 1) * HH);        \
        SN.w2v  = W2[SN.node * HH + j];                                      \
        SN.b1v  = b1[SN.node * HH + j];                                      \
        SN.xv   = x[b * NN + SN.node];                                       \
        SN.b2v  = b2[SN.node];                                               \
        SN.w1xv = Wn_nxt[NN * HH + j];                                       \
        SN.wfr  = Wn_nxt[(nodeT << 5) + j];                                  \
    }                                                                        \
    /* 6: compute-critical section */                                        \
    __builtin_amdgcn_s_setprio(1);                                           \
    float a0 = 0.f, a1 = 0.f, a2 = 0.f, a3 = 0.f;                            \
    _Pragma("unroll")                                                        \
    for (int q = 0; q < 8; q += 2) {                                         \
        a0 += ECUR[q][0]     * wv[2*q];                                      \
        a1 += ECUR[q][2]     * wv[2*q+1];                                    \
        a2 += ECUR[q+1][0]   * wv[2*q+2];                                    \
        a3 += ECUR[q+1][2]   * wv[2*q+3];                                    \
    }                                                                        \
    /* 6b: entries 32..47 — branch-LOCAL fully-defined arrays */             \
    if (SC_cnt_snap > 32) {                                                  \
        f4 e3[4];                                                            \
        const f4* eb3 = (const f4*)&entb[BCUR][half][16];                    \
        _Pragma("unroll")                                                    \
        for (int q = 0; q < 4; ++q) e3[q] = eb3[q];                          \
        float w3[8];                                                         \
        _Pragma("unroll")                                                    \
        for (int q = 0; q < 4; ++q) {                                        \
            w3[2*q]   = *(const float*)(WnB + (__float_as_int(e3[q][1]) + j4));\
            w3[2*q+1] = *(const float*)(WnB + (__float_as_int(e3[q][3]) + j4));\
        }                                                                    \
        _Pragma("unroll")                                                    \
        for (int q = 0; q < 4; ++q) {                                        \
            a0 += e3[q][0] * w3[2*q];                                        \
            a1 += e3[q][2] * w3[2*q+1];                                      \
        }                                                                    \
        /* 6c: entries 48+ (rare statistical tail; correctness guard) */     \
        if (SC_cnt_snap > 48) {                                              \
            for (int i = 24; 2 * i + half < SC_cnt_snap; ++i) {              \
                float2 e = entb[BCUR][half][i];                              \
                a2 += e.x * *(const float*)(WnB + (__float_as_int(e.y) + j4));\
            }                                                                \
        }                                                                    \
    }                                                                        \
    float acc = (a0 + a1) + (a2 + a3);                                       \
    /* 8 */                                                                  \
    float accT = acc + __shfl_xor(acc, 32);                                  \
    const bool fc = ((T) > 0) && (dob != pend_node) &&                       \
        ((((pend_node < 64) ? (SC.bw0 >> pend_node)                          \
                            : (SC.bw1 >> (pend_node - 64)))) & 1ull);        \
    accT += (fc ? pend_val : 0.f) * SC.wfr;                                  \
    accT += SC.xv * SC.w1xv;                                                 \
    accT += SC.b1v;                                                          \
    const float hv = (accT > 0.f) ? accT : 0.01f * accT;                     \
    float pr = hv * SC.w2v;                                                  \
    pr += __int_as_float(__builtin_amdgcn_update_dpp(                        \
             0, __float_as_int(pr), 0xB1, 0xF, 0xF, true));                  \
    pr += __int_as_float(__builtin_amdgcn_update_dpp(                        \
             0, __float_as_int(pr), 0x4E, 0xF, 0xF, true));                  \
    pr += __int_as_float(__builtin_amdgcn_update_dpp(                        \
             0, __float_as_int(pr), 0x141, 0xF, 0xF, true));                 \
    pr += __int_as_float(__builtin_amdgcn_update_dpp(                        \
             0, __float_as_int(pr), 0x140, 0xF, 0xF, true));                 \
    pr += __shfl_xor(pr, 16);                                                \
    const float outv = pr + SC.b2v;                                          \
    __builtin_amdgcn_s_setprio(0);                                           \
    pend_node = nodeT; pend_val = outv;                                      \
  }

__global__ __launch_bounds__(64, 4) void cond_mlp(
    const float* __restrict__ x, const float* __restrict__ u,
    const float* __restrict__ W1, const float* __restrict__ b1,
    const float* __restrict__ W2, const float* __restrict__ b2,
    const int* __restrict__ order, const int* __restrict__ do_idxs,
    const ulonglong2* __restrict__ bitsT, float* __restrict__ out)
{
    const int b = blockIdx.x;
    const int lane = threadIdx.x;
    const int j = lane & 31;
    const int j4 = j << 2;
    const int half = lane >> 5;

    // [buf][entry parity][entry>>1]; inner row 68*8=544B (16B-aligned)
    __shared__ __align__(16) float2 entb[2][2][68];

    const float ub = u[b];
    const int dob = __builtin_amdgcn_readfirstlane(do_idxs[b]);
    float out0 = (dob == lane) ? ub : 0.f;
    float out1 = (dob == lane + 64) ? ub : 0.f;

    unsigned long long nz0 = (dob >= 0 && dob < 64) ? (1ull << dob) : 0ull;
    unsigned long long nz1 = (dob >= 64) ? (1ull << (dob - 64)) : 0ull;

    const int* ord = order + b * NN;
    const ulonglong2* bb = bitsT + (size_t)b * NN;

    const unsigned long long lanebit = 1ull << lane;
    // W1 row BYTE offsets (d * HH * 4 = d<<7)
    const float fidx0 = __int_as_float(lane << 7);
    const float fidx1 = __int_as_float((lane + 64) << 7);

    // ---- prologue: fill SA (step 0) and SB (step 1 prefetch) ----
    Pipe SA, SB;
    SA.node = __builtin_amdgcn_readfirstlane(ord[0]);
    SB.node = __builtin_amdgcn_readfirstlane(ord[1]);
    SB.vb = bb[SB.node];
    SA.vb = bb[SA.node];   // consumed immediately below for step 0's masks

    SA.bw0 = rfl64(SA.vb.x);
    SA.bw1 = rfl64(SA.vb.y);
    f4 eA[8], eB[8];
    {
        const unsigned long long m0 = nz0 & SA.bw0;
        const unsigned long long m1 = nz1 & SA.bw1;
        const int c0 = __popcll(m0);
        SA.cnt = c0 + __popcll(m1);
        const int p0 = mbcnt64(m0);
        if (m0 & lanebit) entb[0][p0 & 1][p0 >> 1] = make_float2(out0, fidx0);
        const int p1 = c0 + mbcnt64(m1);
        if (m1 & lanebit) entb[0][p1 & 1][p1 >> 1] = make_float2(out1, fidx1);
        const int top = (SA.cnt > 32) ? 48 : 32;
        const int pp = SA.cnt + lane;
        if (pp < top) entb[0][pp & 1][pp >> 1] = make_float2(0.f, __int_as_float(0));
        const f4* eb = (const f4*)&entb[0][half][0];
#pragma unroll
        for (int q = 0; q < 8; ++q) eA[q] = eb[q];
    }
    {
        const float* Wn0 = W1 + (size_t)SA.node * ((NN + 1) * HH);
        SA.w2v  = W2[SA.node * HH + j];
        SA.b1v  = b1[SA.node * HH + j];
        SA.xv   = x[b * NN + SA.node];
        SA.b2v  = b2[SA.node];
        SA.w1xv = Wn0[NN * HH + j];
        SA.wfr  = 0.f;
    }

    int pend_node = 0;
    float pend_val = 0.f;

    // ---- main loop: unroll-2 alternates (eA,SA,buf0) / (eB,SB,buf1) ----
    for (int t = 0; t < NN; t += 2) {
        const int SC_cnt_snap0 = SA.cnt;
        { const int SC_cnt_snap = SC_cnt_snap0;
          STEP(t,     eA, eB, SA, SB, 0, 1) }
        const int SC_cnt_snap1 = SB.cnt;
        { const int SC_cnt_snap = SC_cnt_snap1;
          STEP(t + 1, eB, eA, SB, SA, 1, 0) }
    }

    // apply final pending update (from step NN-1)
    if (dob != pend_node && lane == (pend_node & 63)) {
        if (pend_node < 64) out0 = pend_val; else out1 = pend_val;
    }

    out[b * NN + lane] = out0;
    out[b * NN + 64 + lane] = out1;
}

extern "C" void kernel_launch(void* const* d_in, const int* in_sizes, int n_in,
                              void* d_out, int out_size, void* d_ws, size_t ws_size,
                              hipStream_t stream) {
    const float* x   = (const float*)d_in[0];
    const float* A   = (const float*)d_in[1];
    const float* u   = (const float*)d_in[2];
    const float* W1  = (const float*)d_in[3];
    const float* b1  = (const float*)d_in[4];
    const float* W2  = (const float*)d_in[5];
    const float* b2  = (const float*)d_in[6];
    const int* order = (const int*)d_in[7];
    const int* dox   = (const int*)d_in[8];

    ulonglong2* bitsT = (ulonglong2*)d_ws;  // 4096*128*16 B = 8 MB

    pack_bits<<<(BB * 128) / 256, 256, 0, stream>>>(A, bitsT);
    cond_mlp<<<BB, 64, 0, stream>>>(x, u, W1, b1, W2, b2, order, dox,
                                    bitsT, (float*)d_out);
}